// Round 6
// baseline (289.261 us; speedup 1.0000x reference)
//
#include <hip/hip_runtime.h>
#include <math.h>

// Pe_local_based_attention: B=4, H=8, N=4096, K=32, D=8 (fp32)
// R5: attack per-wave serial load latency.
//  - k_mat tile (16KB/block) staged via __builtin_amdgcn_global_load_lds:
//    async DMA with NO VGPR destinations -> all staging loads in flight,
//    one vmcnt drain at the barrier (cannot be register-serialized).
//  - remaining per-lane loads (v float4, re_xyz, q, weights) kept direct,
//    with __launch_bounds__(512,1) relaxing the VGPR cap to 256 so they
//    all get distinct dest registers and issue before the barrier.
//  - one triple per 32-lane group; fold-reduce PV; max-free softmax;
//    deferred softmax divide. (Index math verified by R0/R3 passes.)

#define T_PER_BLOCK 16

__global__ __launch_bounds__(512, 1) void pe_attn_kernel(
    const float* __restrict__ q,       // [B,H,N,1,D]  = t*8
    const float* __restrict__ k_mat,   // [B,H,N,D,K]  = t*256, layout [d][k]
    const float* __restrict__ v,       // [B,H,N,K,D]  = t*256, layout [k][d]
    const float* __restrict__ re_xyz,  // [B,N,K,3]
    const float* __restrict__ w1,      // [3,H]
    const float* __restrict__ b1,      // [H]
    const float* __restrict__ w2,      // [3,64]
    const float* __restrict__ b2,      // [64]
    float* __restrict__ out)           // [B,N,H,D]
{
    __shared__ __align__(16) float lds_k[T_PER_BLOCK * 256]; // 16 KB

    const int tid  = threadIdx.x;
    const int wave = tid >> 6;     // 0..7
    const int lane = tid & 63;     // 0..63
    const int t0   = blockIdx.x * T_PER_BLOCK;

    // ---- async DMA: k_mat block tile -> LDS, 1KB per call, 2 calls/wave ----
    // HW writes lds_base + lane*16; source is per-lane. Linear both sides.
    #pragma unroll
    for (int j = 0; j < 2; ++j) {
        const int seg = wave * 2 + j;  // 0..15, 256 floats each
        __builtin_amdgcn_global_load_lds(
            (const __attribute__((address_space(1))) void*)
                (k_mat + (size_t)t0 * 256 + seg * 256 + lane * 4),
            (__attribute__((address_space(3))) void*)(lds_k + seg * 256),
            16, 0, 0);
    }

    const int it  = tid >> 5;      // triple slot, 0..15
    const int k   = tid & 31;      // neighbor index
    const int t   = t0 + it;
    const int b   = t >> 15;       // H*N = 32768
    const int rem = t & 32767;
    const int h   = rem >> 12;
    const int n   = rem & 4095;

    // ---- direct per-lane loads, all issued before the barrier ----
    // v row k (lane-private, no sharing -> no LDS staging)
    const float* vbase = v + (size_t)t * 256 + k * 8;
    const float4 v0 = ((const float4*)vbase)[0];
    const float4 v1 = ((const float4*)vbase)[1];

    // re_xyz for score bias
    const size_t rxb = ((size_t)((b << 12) + n) * 32 + k) * 3;
    const float rx0 = re_xyz[rxb], rx1 = re_xyz[rxb + 1], rx2 = re_xyz[rxb + 2];

    // re_xyz for v_xyz (raw-reshape decode)
    const int n2 = rem >> 3;
    const int k2 = ((rem & 7) << 2) + (k >> 3);
    const size_t rxb2 = ((size_t)((b << 12) + n2) * 32 + k2) * 3;
    const float s0 = re_xyz[rxb2], s1 = re_xyz[rxb2 + 1], s2 = re_xyz[rxb2 + 2];

    // q (32-lane broadcast, L1-served)
    const float4 qa = ((const float4*)(q + (size_t)t * 8))[0];
    const float4 qb = ((const float4*)(q + (size_t)t * 8))[1];

    // weights (grid-constant, L1-resident)
    const float wq0 = w1[h], wq1 = w1[8 + h], wq2 = w1[16 + h], bq = b1[h];
    const int c0 = (k & 7) << 3;
    const float4 wr0a = ((const float4*)(w2 + c0))[0];
    const float4 wr0b = ((const float4*)(w2 + c0))[1];
    const float4 wr1a = ((const float4*)(w2 + 64 + c0))[0];
    const float4 wr1b = ((const float4*)(w2 + 64 + c0))[1];
    const float4 wr2a = ((const float4*)(w2 + 128 + c0))[0];
    const float4 wr2b = ((const float4*)(w2 + 128 + c0))[1];
    const float4 bba  = ((const float4*)(b2 + c0))[0];
    const float4 bbb  = ((const float4*)(b2 + c0))[1];

    __syncthreads();  // drains the DMA (vmcnt) + makes LDS visible

    // ---- energy = q . k_col + bias, scaled (LDS column read: 2-way, free) ----
    const float* kt = lds_k + it * 256;
    float e = qa.x * kt[k]
            + qa.y * kt[32  + k]
            + qa.z * kt[64  + k]
            + qa.w * kt[96  + k]
            + qb.x * kt[128 + k]
            + qb.y * kt[160 + k]
            + qb.z * kt[192 + k]
            + qb.w * kt[224 + k];
    e += rx0 * wq0 + rx1 * wq1 + rx2 * wq2 + bq;
    e *= 0.35355339059327373f; // 1/sqrt(D)
    const float p = __expf(e); // no max-sub: |e| <= ~6, fp32-safe

    // ---- softmax denominator: 5-shuffle butterfly ----
    float s = p;
    #pragma unroll
    for (int off = 16; off; off >>= 1) s += __shfl_xor(s, off);

    // ---- weighted values (divide deferred) ----
    float pd[8];
    pd[0] = p * (v0.x + s0 * wr0a.x + s1 * wr1a.x + s2 * wr2a.x + bba.x);
    pd[1] = p * (v0.y + s0 * wr0a.y + s1 * wr1a.y + s2 * wr2a.y + bba.y);
    pd[2] = p * (v0.z + s0 * wr0a.z + s1 * wr1a.z + s2 * wr2a.z + bba.z);
    pd[3] = p * (v0.w + s0 * wr0a.w + s1 * wr1a.w + s2 * wr2a.w + bba.w);
    pd[4] = p * (v1.x + s0 * wr0b.x + s1 * wr1b.x + s2 * wr2b.x + bbb.x);
    pd[5] = p * (v1.y + s0 * wr0b.y + s1 * wr1b.y + s2 * wr2b.y + bbb.y);
    pd[6] = p * (v1.z + s0 * wr0b.z + s1 * wr1b.z + s2 * wr2b.z + bbb.z);
    pd[7] = p * (v1.w + s0 * wr0b.w + s1 * wr1b.w + s2 * wr2b.w + bbb.w);

    // ---- fold-reduce: 32-lane sum while narrowing 8 values -> 1 ----
    // After the 3 folds, lane holds value d = (k>>2)&7.
    {
        const bool hb = (k & 16) != 0;
        #pragma unroll
        for (int j = 0; j < 4; ++j) {
            float send = hb ? pd[j] : pd[j + 4];
            float recv = __shfl_xor(send, 16);
            pd[j] = (hb ? pd[j + 4] : pd[j]) + recv;
        }
    }
    {
        const bool hb = (k & 8) != 0;
        #pragma unroll
        for (int j = 0; j < 2; ++j) {
            float send = hb ? pd[j] : pd[j + 2];
            float recv = __shfl_xor(send, 8);
            pd[j] = (hb ? pd[j + 2] : pd[j]) + recv;
        }
    }
    {
        const bool hb = (k & 4) != 0;
        float send = hb ? pd[0] : pd[1];
        float recv = __shfl_xor(send, 4);
        pd[0] = (hb ? pd[1] : pd[0]) + recv;
    }
    pd[0] += __shfl_xor(pd[0], 2);
    pd[0] += __shfl_xor(pd[0], 1);

    // ---- final scale by 1/s (lane-uniform) and store ----
    if ((k & 3) == 0) {
        const int d = (k >> 2) & 7;
        out[((size_t)((b << 12) + n) * 8 + h) * 8 + d] =
            pd[0] * __builtin_amdgcn_rcpf(s);
    }
}

extern "C" void kernel_launch(void* const* d_in, const int* in_sizes, int n_in,
                              void* d_out, int out_size, void* d_ws, size_t ws_size,
                              hipStream_t stream) {
    const float* q      = (const float*)d_in[0];
    const float* k_mat  = (const float*)d_in[1];
    const float* v      = (const float*)d_in[2];
    const float* re_xyz = (const float*)d_in[3];
    const float* w1     = (const float*)d_in[4];
    const float* b1     = (const float*)d_in[5];
    const float* w2     = (const float*)d_in[6];
    const float* b2     = (const float*)d_in[7];
    float* out = (float*)d_out;

    dim3 grid(131072 / T_PER_BLOCK), block(512);
    hipLaunchKernelGGL(pe_attn_kernel, grid, block, 0, stream,
                       q, k_mat, v, re_xyz, w1, b1, w2, b2, out);
}